// Round 5
// baseline (375.535 us; speedup 1.0000x reference)
//
#include <hip/hip_runtime.h>
#include <hip/hip_bf16.h>
#include <math.h>

typedef __bf16 bf16;
typedef __bf16 bf16x8 __attribute__((ext_vector_type(8)));
typedef float  f32x4  __attribute__((ext_vector_type(4)));
typedef unsigned int u32;

#define NROWS 16384
#define KDIM  2048
#define NCOLS 2048

// ---------------- workspace layout ----------------
#define OFF_XBF   0
#define OFF_Q     67108864
#define OFF_EBF   75497472
#define OFF_PART  83886080
#define OFF_SCALE 83894272

__device__ __forceinline__ void gload16(const bf16* g, bf16* l) {
    __builtin_amdgcn_global_load_lds(
        (const __attribute__((address_space(1))) u32*)g,
        (__attribute__((address_space(3))) u32*)l,
        16, 0, 0);
}

__device__ __forceinline__ void BAR() {
    asm volatile("" ::: "memory");
    __builtin_amdgcn_s_barrier();
    asm volatile("" ::: "memory");
}

// ---- 1) per-row sum of |W| (deterministic fixed-order) ----
__global__ void k_rowsum_absW(const float* __restrict__ W, float* __restrict__ partials) {
    int row = blockIdx.x;
    int t = threadIdx.x;
    const float4* wr = (const float4*)(W + (size_t)row * KDIM);
    float4 a = wr[t * 2];
    float4 b = wr[t * 2 + 1];
    float s = fabsf(a.x) + fabsf(a.y) + fabsf(a.z) + fabsf(a.w)
            + fabsf(b.x) + fabsf(b.y) + fabsf(b.z) + fabsf(b.w);
    __shared__ float red[256];
    red[t] = s; __syncthreads();
    for (int off = 128; off > 0; off >>= 1) {
        if (t < off) red[t] += red[t + off];
        __syncthreads();
    }
    if (t == 0) partials[row] = red[0];
}

// ---- 2) finalize scale = max(mean|W|, 1e-8) ----
__global__ void k_scale(const float* __restrict__ partials, float* __restrict__ scale) {
    int t = threadIdx.x;
    double s = 0.0;
    for (int i = t; i < 2048; i += 256) s += (double)partials[i];
    __shared__ double red[256];
    red[t] = s; __syncthreads();
    for (int off = 128; off > 0; off >>= 1) {
        if (t < off) red[t] += red[t + off];
        __syncthreads();
    }
    if (t == 0) {
        float m = (float)(red[0] / 4194304.0);  // 2048*2048
        scale[0] = fmaxf(m, 1e-8f);
    }
}

// ---- 3) ternary-quantize W -> q (bf16 in {-1,0,+1}), cast We -> bf16 ----
__global__ void k_quant(const float* __restrict__ W, const float* __restrict__ We,
                        const float* __restrict__ scale_p,
                        bf16* __restrict__ q, bf16* __restrict__ ebf) {
    float scale = scale_p[0];
    size_t base = ((size_t)blockIdx.x * 256 + threadIdx.x) * 8;
    float4 w0 = *(const float4*)(W + base);
    float4 w1 = *(const float4*)(W + base + 4);
    float4 e0 = *(const float4*)(We + base);
    float4 e1 = *(const float4*)(We + base + 4);
    float wv[8] = {w0.x, w0.y, w0.z, w0.w, w1.x, w1.y, w1.z, w1.w};
    float ev[8] = {e0.x, e0.y, e0.z, e0.w, e1.x, e1.y, e1.z, e1.w};
    bf16x8 qv, bv;
#pragma unroll
    for (int i = 0; i < 8; i++) {
        float ws = wv[i] / scale;
        float qq = ws > 0.3f ? 1.0f : (ws < -0.3f ? -1.0f : 0.0f);
        qv[i] = (bf16)qq;
        bv[i] = (bf16)ev[i];
    }
    *(bf16x8*)(q + base)   = qv;
    *(bf16x8*)(ebf + base) = bv;
}

// ---- 4) x fp32 -> bf16 ----
__global__ void k_cvt_x(const float* __restrict__ x, bf16* __restrict__ xbf) {
    size_t base = ((size_t)blockIdx.x * 256 + threadIdx.x) * 8;
    float4 a = *(const float4*)(x + base);
    float4 c = *(const float4*)(x + base + 4);
    float v[8] = {a.x, a.y, a.z, a.w, c.x, c.y, c.z, c.w};
    bf16x8 o;
#pragma unroll
    for (int i = 0; i < 8; i++) o[i] = (bf16)v[i];
    *(bf16x8*)(xbf + base) = o;
}

// ---- 5) fused dual GEMM: y = relu(scale*(x@q^T) + b) + x@We^T + be ----
// R2-verified geometry: 128x128 tile, BK=64, 8 waves (2M x 4N), 64x32 dual
// per wave. NEW sync skeleton: 3 LDS buffers (144KB), depth-2 prefetch,
// counted vmcnt (never 0 in main loop; T4), raw s_barrier, setprio (T5),
// XCD swizzle (T1). T2 LDS XOR swizzle unchanged (verified 0-conflict):
// physical elem = row*64 + (col ^ ((row&7)<<3)); global SOURCE col
// pre-swizzled since global_load_lds writes linearly (rule #21).
#define BM 128
#define BN 128
#define BK 64
#define KSTEPS (KDIM / BK)        // 32
#define BUFE (BM * BK + 2 * BN * BK)  // 24576 elems per buffer

__global__ __launch_bounds__(512)
void k_gemm_dual(const bf16* __restrict__ X, const bf16* __restrict__ Q,
                 const bf16* __restrict__ E,
                 const float* __restrict__ b, const float* __restrict__ be,
                 const float* __restrict__ scale_p, float* __restrict__ Y)
{
    __shared__ bf16 lds[3][BUFE];   // 144 KB

    int t    = threadIdx.x;
    int lane = t & 63;
    int w    = t >> 6;      // 0..7
    int wr   = w >> 2;      // 0..1  (64-row block)
    int wc   = w & 3;       // 0..3  (32-col block)

    // T1: bijective XCD swizzle (2048 blocks, 2048 % 8 == 0)
    int id   = blockIdx.x;                 // 0..2047
    int swz  = (id & 7) * 256 + (id >> 3);
    int bRow = swz >> 4;                   // 0..127
    int bCol = swz & 15;                   // 0..15

    const bf16* gA  = X + (size_t)(bRow * BM) * KDIM;
    const bf16* gB1 = Q + (size_t)(bCol * BN) * KDIM;
    const bf16* gB2 = E + (size_t)(bCol * BN) * KDIM;

    int row0 = t >> 3;                       // 0..63
    // pre-swizzled global source column (elements):
    int colsw = ((t & 7) * 8) ^ ((row0 & 7) << 3);

    f32x4 acc1[4][2], acc2[4][2];
#pragma unroll
    for (int m = 0; m < 4; m++)
#pragma unroll
        for (int n = 0; n < 2; n++) {
            acc1[m][n] = (f32x4){0.f, 0.f, 0.f, 0.f};
            acc2[m][n] = (f32x4){0.f, 0.f, 0.f, 0.f};
        }

    int lrow = lane & 15;
    int lk   = lane >> 4;   // 0..3

    // stage K-tile ks into buffer buf: 6 gload_lds per thread (2 A, 2 B1, 2 B2)
    auto STAGE = [&](int buf, int ks) {
        bf16* LA  = &lds[buf][0];
        bf16* LB1 = &lds[buf][BM * BK];
        bf16* LB2 = &lds[buf][BM * BK + BN * BK];
        size_t kof = (size_t)ks * BK + colsw;
        gload16(gA  + (size_t)row0 * KDIM + kof,        &LA [t * 8]);
        gload16(gA  + (size_t)(row0 + 64) * KDIM + kof, &LA [(512 + t) * 8]);
        gload16(gB1 + (size_t)row0 * KDIM + kof,        &LB1[t * 8]);
        gload16(gB1 + (size_t)(row0 + 64) * KDIM + kof, &LB1[(512 + t) * 8]);
        gload16(gB2 + (size_t)row0 * KDIM + kof,        &LB2[t * 8]);
        gload16(gB2 + (size_t)(row0 + 64) * KDIM + kof, &LB2[(512 + t) * 8]);
    };

    auto COMPUTE = [&](int buf) {
        const bf16* LA  = &lds[buf][0];
        const bf16* LB1 = &lds[buf][BM * BK];
        const bf16* LB2 = &lds[buf][BM * BK + BN * BK];
#pragma unroll
        for (int kk = 0; kk < 2; kk++) {
            int ko = kk * 32 + lk * 8;       // logical k-offset (elements)
            bf16x8 af[4], bq[2], beo[2];
#pragma unroll
            for (int m = 0; m < 4; m++) {
                int ar = wr * 64 + m * 16 + lrow;
                af[m] = *(const bf16x8*)&LA[ar * BK + (ko ^ ((ar & 7) << 3))];
            }
#pragma unroll
            for (int n = 0; n < 2; n++) {
                int br = wc * 32 + n * 16 + lrow;
                int sc = ko ^ ((br & 7) << 3);
                bq [n] = *(const bf16x8*)&LB1[br * BK + sc];
                beo[n] = *(const bf16x8*)&LB2[br * BK + sc];
            }
            __builtin_amdgcn_s_setprio(1);
#pragma unroll
            for (int m = 0; m < 4; m++)
#pragma unroll
                for (int n = 0; n < 2; n++) {
                    acc1[m][n] = __builtin_amdgcn_mfma_f32_16x16x32_bf16(af[m], bq [n], acc1[m][n], 0, 0, 0);
                    acc2[m][n] = __builtin_amdgcn_mfma_f32_16x16x32_bf16(af[m], beo[n], acc2[m][n], 0, 0, 0);
                }
            __builtin_amdgcn_s_setprio(0);
        }
    };

    // ---- depth-2 pipeline with counted vmcnt (T4): 12 loads stay in flight ----
    STAGE(0, 0);
    STAGE(1, 1);

#pragma unroll 1
    for (int T = 0; T < KSTEPS - 2; ++T) {   // T = 0..29
        STAGE((T + 2) % 3, T + 2);
        // outstanding: {T:6, T+1:6, T+2:6} -> retire oldest 6 = tile T
        asm volatile("s_waitcnt vmcnt(12)" ::: "memory");
        BAR();
        COMPUTE(T % 3);
        asm volatile("s_waitcnt lgkmcnt(0)" ::: "memory");
        BAR();
    }
    // T = 30: outstanding {30:<=6, 31:6} -> retire tile 30
    asm volatile("s_waitcnt vmcnt(6)" ::: "memory");
    BAR();
    COMPUTE((KSTEPS - 2) % 3);   // 30 % 3 = 0
    asm volatile("s_waitcnt lgkmcnt(0)" ::: "memory");
    BAR();
    // T = 31: last tile
    asm volatile("s_waitcnt vmcnt(0)" ::: "memory");
    BAR();
    COMPUTE((KSTEPS - 1) % 3);   // 31 % 3 = 1

    float scale = scale_p[0];
    // C/D layout (16x16x32): col = lane&15, row = (lane>>4)*4 + reg
#pragma unroll
    for (int m = 0; m < 4; m++) {
        int gr0 = bRow * BM + wr * 64 + m * 16 + (lane >> 4) * 4;
#pragma unroll
        for (int n = 0; n < 2; n++) {
            int gc = bCol * BN + wc * 32 + n * 16 + (lane & 15);
            float bj  = b[gc];
            float bej = be[gc];
#pragma unroll
            for (int v = 0; v < 4; v++) {
                float chain = fmaxf(acc1[m][n][v] * scale + bj, 0.0f);
                float y = chain + acc2[m][n][v] + bej;
                Y[(size_t)(gr0 + v) * NCOLS + gc] = y;
            }
        }
    }
}

// ---- 6) per-row fake-int8 quantization, in place on d_out ----
__global__ void k_quant_rows(float* __restrict__ Y) {
    int row = blockIdx.x;
    int t = threadIdx.x;
    float4* yv = (float4*)(Y + (size_t)row * NCOLS);
    float4 a = yv[t];
    float4 c = yv[t + 256];
    float mx = fmaxf(fmaxf(fmaxf(fabsf(a.x), fabsf(a.y)), fmaxf(fabsf(a.z), fabsf(a.w))),
                     fmaxf(fmaxf(fabsf(c.x), fabsf(c.y)), fmaxf(fabsf(c.z), fabsf(c.w))));
    __shared__ float red[256];
    red[t] = mx; __syncthreads();
    for (int off = 128; off > 0; off >>= 1) {
        if (t < off) red[t] = fmaxf(red[t], red[t + off]);
        __syncthreads();
    }
    float m = fmaxf(red[0], 1e-5f);
    float qs = 127.0f / m;
    float4 oa, oc;
    oa.x = rintf(fminf(fmaxf(a.x * qs, -127.f), 127.f)) / qs;
    oa.y = rintf(fminf(fmaxf(a.y * qs, -127.f), 127.f)) / qs;
    oa.z = rintf(fminf(fmaxf(a.z * qs, -127.f), 127.f)) / qs;
    oa.w = rintf(fminf(fmaxf(a.w * qs, -127.f), 127.f)) / qs;
    oc.x = rintf(fminf(fmaxf(c.x * qs, -127.f), 127.f)) / qs;
    oc.y = rintf(fminf(fmaxf(c.y * qs, -127.f), 127.f)) / qs;
    oc.z = rintf(fminf(fmaxf(c.z * qs, -127.f), 127.f)) / qs;
    oc.w = rintf(fminf(fmaxf(c.w * qs, -127.f), 127.f)) / qs;
    yv[t] = oa;
    yv[t + 256] = oc;
}

extern "C" void kernel_launch(void* const* d_in, const int* in_sizes, int n_in,
                              void* d_out, int out_size, void* d_ws, size_t ws_size,
                              hipStream_t stream) {
    const float* x  = (const float*)d_in[0];
    const float* W  = (const float*)d_in[1];
    const float* b  = (const float*)d_in[2];
    const float* We = (const float*)d_in[3];
    const float* be = (const float*)d_in[4];
    float* out = (float*)d_out;

    char* ws = (char*)d_ws;
    bf16*  xbf      = (bf16*)(ws + OFF_XBF);
    bf16*  q        = (bf16*)(ws + OFF_Q);
    bf16*  ebf      = (bf16*)(ws + OFF_EBF);
    float* partials = (float*)(ws + OFF_PART);
    float* scale    = (float*)(ws + OFF_SCALE);

    k_rowsum_absW<<<2048, 256, 0, stream>>>(W, partials);
    k_scale<<<1, 256, 0, stream>>>(partials, scale);
    k_quant<<<2048, 256, 0, stream>>>(W, We, scale, q, ebf);
    k_cvt_x<<<16384, 256, 0, stream>>>(x, xbf);

    k_gemm_dual<<<(NROWS / BM) * (NCOLS / BN), 512, 0, stream>>>(xbf, q, ebf, b, be, scale, out);

    k_quant_rows<<<NROWS, 256, 0, stream>>>(out);
}

// Round 6
// 350.263 us; speedup vs baseline: 1.0722x; 1.0722x over previous
//
#include <hip/hip_runtime.h>
#include <hip/hip_bf16.h>
#include <math.h>

typedef __bf16 bf16;
typedef __bf16 bf16x8 __attribute__((ext_vector_type(8)));
typedef float  f32x16 __attribute__((ext_vector_type(16)));
typedef unsigned int u32;

#define NROWS 16384
#define KDIM  2048
#define NCOLS 2048

// ---------------- workspace layout ----------------
#define OFF_XBF   0
#define OFF_Q     67108864
#define OFF_EBF   75497472
#define OFF_PART  83886080
#define OFF_SCALE 83894272

__device__ __forceinline__ void gload16(const bf16* g, bf16* l) {
    __builtin_amdgcn_global_load_lds(
        (const __attribute__((address_space(1))) u32*)g,
        (__attribute__((address_space(3))) u32*)l,
        16, 0, 0);
}

// ---- 1) per-row sum of |W| (deterministic fixed-order) ----
__global__ void k_rowsum_absW(const float* __restrict__ W, float* __restrict__ partials) {
    int row = blockIdx.x;
    int t = threadIdx.x;
    const float4* wr = (const float4*)(W + (size_t)row * KDIM);
    float4 a = wr[t * 2];
    float4 b = wr[t * 2 + 1];
    float s = fabsf(a.x) + fabsf(a.y) + fabsf(a.z) + fabsf(a.w)
            + fabsf(b.x) + fabsf(b.y) + fabsf(b.z) + fabsf(b.w);
    __shared__ float red[256];
    red[t] = s; __syncthreads();
    for (int off = 128; off > 0; off >>= 1) {
        if (t < off) red[t] += red[t + off];
        __syncthreads();
    }
    if (t == 0) partials[row] = red[0];
}

// ---- 2) finalize scale = max(mean|W|, 1e-8) ----
__global__ void k_scale(const float* __restrict__ partials, float* __restrict__ scale) {
    int t = threadIdx.x;
    double s = 0.0;
    for (int i = t; i < 2048; i += 256) s += (double)partials[i];
    __shared__ double red[256];
    red[t] = s; __syncthreads();
    for (int off = 128; off > 0; off >>= 1) {
        if (t < off) red[t] += red[t + off];
        __syncthreads();
    }
    if (t == 0) {
        float m = (float)(red[0] / 4194304.0);  // 2048*2048
        scale[0] = fmaxf(m, 1e-8f);
    }
}

// ---- 3) ternary-quantize W -> q (bf16 in {-1,0,+1}), cast We -> bf16 ----
__global__ void k_quant(const float* __restrict__ W, const float* __restrict__ We,
                        const float* __restrict__ scale_p,
                        bf16* __restrict__ q, bf16* __restrict__ ebf) {
    float scale = scale_p[0];
    size_t base = ((size_t)blockIdx.x * 256 + threadIdx.x) * 8;
    float4 w0 = *(const float4*)(W + base);
    float4 w1 = *(const float4*)(W + base + 4);
    float4 e0 = *(const float4*)(We + base);
    float4 e1 = *(const float4*)(We + base + 4);
    float wv[8] = {w0.x, w0.y, w0.z, w0.w, w1.x, w1.y, w1.z, w1.w};
    float ev[8] = {e0.x, e0.y, e0.z, e0.w, e1.x, e1.y, e1.z, e1.w};
    bf16x8 qv, bv;
#pragma unroll
    for (int i = 0; i < 8; i++) {
        float ws = wv[i] / scale;
        float qq = ws > 0.3f ? 1.0f : (ws < -0.3f ? -1.0f : 0.0f);
        qv[i] = (bf16)qq;
        bv[i] = (bf16)ev[i];
    }
    *(bf16x8*)(q + base)   = qv;
    *(bf16x8*)(ebf + base) = bv;
}

// ---- 4) x fp32 -> bf16 ----
__global__ void k_cvt_x(const float* __restrict__ x, bf16* __restrict__ xbf) {
    size_t base = ((size_t)blockIdx.x * 256 + threadIdx.x) * 8;
    float4 a = *(const float4*)(x + base);
    float4 c = *(const float4*)(x + base + 4);
    float v[8] = {a.x, a.y, a.z, a.w, c.x, c.y, c.z, c.w};
    bf16x8 o;
#pragma unroll
    for (int i = 0; i < 8; i++) o[i] = (bf16)v[i];
    *(bf16x8*)(xbf + base) = o;
}

// ---- 5) fused dual GEMM: y = relu(scale*(x@q^T) + b) + x@We^T + be ----
// R2-verified skeleton: 128x128 tile, BK=64, 8 waves (2M x 4N), 64x32 dual
// per wave, single 48KB LDS buffer (3 blocks/CU), 2 barriers/K-step,
// natural grid (16,128). ONLY change vs R2: 32x32x16 MFMA (fewer, fatter
// matrix ops; same LDS traffic). T2 LDS XOR swizzle unchanged (0-conflict):
// physical elem = row*64 + (col ^ ((row&7)<<3)); global SOURCE col is
// pre-swizzled since global_load_lds writes linearly (rule #21).
// 32x32x16 layouts: A/B lane l -> row/col = l&31, k = (l>>5)*8 + j.
// C/D reg r -> row = (r&3) + 8*(r>>2) + 4*(lane>>5), col = lane&31 (m74/m101).
#define BM 128
#define BN 128
#define BK 64

__global__ __launch_bounds__(512)
void k_gemm_dual(const bf16* __restrict__ X, const bf16* __restrict__ Q,
                 const bf16* __restrict__ E,
                 const float* __restrict__ b, const float* __restrict__ be,
                 const float* __restrict__ scale_p, float* __restrict__ Y)
{
    __shared__ bf16 lA [BM * BK];
    __shared__ bf16 lB1[BN * BK];
    __shared__ bf16 lB2[BN * BK];

    int t    = threadIdx.x;
    int lane = t & 63;
    int w    = t >> 6;      // 0..7
    int wr   = w >> 2;      // 0..1  (64-row block)
    int wc   = w & 3;       // 0..3  (32-col block)

    int bCol = blockIdx.x;  // 0..15
    int bRow = blockIdx.y;  // 0..127

    const bf16* gA  = X + (size_t)(bRow * BM) * KDIM;
    const bf16* gB1 = Q + (size_t)(bCol * BN) * KDIM;
    const bf16* gB2 = E + (size_t)(bCol * BN) * KDIM;

    int row0 = t >> 3;                       // 0..63
    // pre-swizzled global source column (elements):
    int colsw = ((t & 7) * 8) ^ ((row0 & 7) << 3);

    f32x16 acc1[2], acc2[2];
#pragma unroll
    for (int m = 0; m < 2; m++) {
        acc1[m] = (f32x16)(0.f);
        acc2[m] = (f32x16)(0.f);
    }

    int l31 = lane & 31;
    int lk8 = (lane >> 5) * 8;   // 0 or 8

    for (int k0 = 0; k0 < KDIM; k0 += BK) {
#pragma unroll
        for (int it = 0; it < 2; ++it) {
            int row = row0 + it * 64;        // (it*64 doesn't change row&7)
            int off = (it * 512 + t) * 8;    // linear LDS dest (elements)
            gload16(gA  + (size_t)row * KDIM + k0 + colsw, &lA [off]);
            gload16(gB1 + (size_t)row * KDIM + k0 + colsw, &lB1[off]);
            gload16(gB2 + (size_t)row * KDIM + k0 + colsw, &lB2[off]);
        }
        __syncthreads();   // drains vmcnt -> staged data visible

#pragma unroll
        for (int ks = 0; ks < 4; ks++) {
            int ko = ks * 16 + lk8;          // logical k-offset (elements)
            bf16x8 af[2], bq, beo;
#pragma unroll
            for (int m = 0; m < 2; m++) {
                int ar = wr * 64 + m * 32 + l31;
                af[m] = *(const bf16x8*)&lA[ar * BK + (ko ^ ((ar & 7) << 3))];
            }
            {
                int br = wc * 32 + l31;
                int sc = ko ^ ((br & 7) << 3);
                bq  = *(const bf16x8*)&lB1[br * BK + sc];
                beo = *(const bf16x8*)&lB2[br * BK + sc];
            }
            __builtin_amdgcn_s_setprio(1);
#pragma unroll
            for (int m = 0; m < 2; m++) {
                acc1[m] = __builtin_amdgcn_mfma_f32_32x32x16_bf16(af[m], bq,  acc1[m], 0, 0, 0);
                acc2[m] = __builtin_amdgcn_mfma_f32_32x32x16_bf16(af[m], beo, acc2[m], 0, 0, 0);
            }
            __builtin_amdgcn_s_setprio(0);
        }
        __syncthreads();
    }

    float scale = scale_p[0];
    // C/D layout (32x32x16): col = lane&31, row = (r&3) + 8*(r>>2) + 4*(lane>>5)
#pragma unroll
    for (int m = 0; m < 2; m++) {
        int gr_base = bRow * BM + wr * 64 + m * 32 + 4 * (lane >> 5);
        int gc = bCol * BN + wc * 32 + l31;
        float bj  = b[gc];
        float bej = be[gc];
#pragma unroll
        for (int r = 0; r < 16; r++) {
            int gr = gr_base + (r & 3) + 8 * (r >> 2);
            float chain = fmaxf(acc1[m][r] * scale + bj, 0.0f);
            float y = chain + acc2[m][r] + bej;
            Y[(size_t)gr * NCOLS + gc] = y;
        }
    }
}

// ---- 6) per-row fake-int8 quantization, in place on d_out ----
__global__ void k_quant_rows(float* __restrict__ Y) {
    int row = blockIdx.x;
    int t = threadIdx.x;
    float4* yv = (float4*)(Y + (size_t)row * NCOLS);
    float4 a = yv[t];
    float4 c = yv[t + 256];
    float mx = fmaxf(fmaxf(fmaxf(fabsf(a.x), fabsf(a.y)), fmaxf(fabsf(a.z), fabsf(a.w))),
                     fmaxf(fmaxf(fabsf(c.x), fabsf(c.y)), fmaxf(fabsf(c.z), fabsf(c.w))));
    __shared__ float red[256];
    red[t] = mx; __syncthreads();
    for (int off = 128; off > 0; off >>= 1) {
        if (t < off) red[t] = fmaxf(red[t], red[t + off]);
        __syncthreads();
    }
    float m = fmaxf(red[0], 1e-5f);
    float qs = 127.0f / m;
    float4 oa, oc;
    oa.x = rintf(fminf(fmaxf(a.x * qs, -127.f), 127.f)) / qs;
    oa.y = rintf(fminf(fmaxf(a.y * qs, -127.f), 127.f)) / qs;
    oa.z = rintf(fminf(fmaxf(a.z * qs, -127.f), 127.f)) / qs;
    oa.w = rintf(fminf(fmaxf(a.w * qs, -127.f), 127.f)) / qs;
    oc.x = rintf(fminf(fmaxf(c.x * qs, -127.f), 127.f)) / qs;
    oc.y = rintf(fminf(fmaxf(c.y * qs, -127.f), 127.f)) / qs;
    oc.z = rintf(fminf(fmaxf(c.z * qs, -127.f), 127.f)) / qs;
    oc.w = rintf(fminf(fmaxf(c.w * qs, -127.f), 127.f)) / qs;
    yv[t] = oa;
    yv[t + 256] = oc;
}

extern "C" void kernel_launch(void* const* d_in, const int* in_sizes, int n_in,
                              void* d_out, int out_size, void* d_ws, size_t ws_size,
                              hipStream_t stream) {
    const float* x  = (const float*)d_in[0];
    const float* W  = (const float*)d_in[1];
    const float* b  = (const float*)d_in[2];
    const float* We = (const float*)d_in[3];
    const float* be = (const float*)d_in[4];
    float* out = (float*)d_out;

    char* ws = (char*)d_ws;
    bf16*  xbf      = (bf16*)(ws + OFF_XBF);
    bf16*  q        = (bf16*)(ws + OFF_Q);
    bf16*  ebf      = (bf16*)(ws + OFF_EBF);
    float* partials = (float*)(ws + OFF_PART);
    float* scale    = (float*)(ws + OFF_SCALE);

    k_rowsum_absW<<<2048, 256, 0, stream>>>(W, partials);
    k_scale<<<1, 256, 0, stream>>>(partials, scale);
    k_quant<<<2048, 256, 0, stream>>>(W, We, scale, q, ebf);
    k_cvt_x<<<16384, 256, 0, stream>>>(x, xbf);

    dim3 g(NCOLS / BN, NROWS / BM);   // (16, 128)
    k_gemm_dual<<<g, 512, 0, stream>>>(xbf, q, ebf, b, be, scale, out);

    k_quant_rows<<<NROWS, 256, 0, stream>>>(out);
}